// Round 1
// baseline (1676.622 us; speedup 1.0000x reference)
//
#include <hip/hip_runtime.h>

#define NN 50000
#define NE 800000
#define NG 256
#define DD 256
#define NL 3
#define BN_EPS 1e-5f

// ---------- utility ----------
__global__ void k_zero(int* p, int n) {
    int i = blockIdx.x * blockDim.x + threadIdx.x;
    if (i < n) p[i] = 0;
}

// count in-degree per dst node and nodes per graph
__global__ void k_count(const int* __restrict__ ei, int* __restrict__ deg,
                        int* __restrict__ gcount, const int* __restrict__ batch) {
    int e = blockIdx.x * blockDim.x + threadIdx.x;
    if (e < NE) atomicAdd(&deg[ei[NE + e]], 1);   // dst row of edge_index
    if (e < NN) atomicAdd(&gcount[batch[e]], 1);
}

// single-block exclusive scan (n <= ~64k). out has n+1 entries (out[n]=total).
__global__ void k_scan(const int* __restrict__ in, int* __restrict__ out,
                       int* __restrict__ cursor, int n) {
    __shared__ int tsum[256];
    int t = threadIdx.x;
    int chunk = (n + 255) / 256;
    int lo = t * chunk;
    int hi = min(lo + chunk, n);
    int s = 0;
    for (int i = lo; i < hi; ++i) s += in[i];
    tsum[t] = s;
    __syncthreads();
    if (t == 0) {
        int acc = 0;
        for (int i = 0; i < 256; ++i) { int v = tsum[i]; tsum[i] = acc; acc += v; }
    }
    __syncthreads();
    int acc = tsum[t];
    for (int i = lo; i < hi; ++i) {
        out[i] = acc;
        if (cursor) cursor[i] = acc;
        acc += in[i];
    }
    if (hi == n) out[n] = acc;   // total (same value from any thread past the end)
}

__global__ void k_scatter(const int* __restrict__ ei, int* __restrict__ cursor,
                          int* __restrict__ elist) {
    int e = blockIdx.x * blockDim.x + threadIdx.x;
    if (e >= NE) return;
    int s = ei[e];          // src
    int d = ei[NE + e];     // dst
    int pos = atomicAdd(&cursor[d], 1);
    elist[pos] = s;
}

// z0[node] = h[node] + sum_{src in CSR[node]} h[src]   (one wave per node, float4/lane)
__global__ __launch_bounds__(64) void k_agg(const float* __restrict__ h,
                                            const int* __restrict__ row_start,
                                            const int* __restrict__ elist,
                                            float* __restrict__ z0) {
    int node = blockIdx.x;
    int lane = threadIdx.x;
    const float4* h4 = (const float4*)h;
    float4 acc = h4[node * 64 + lane];
    int lo = row_start[node], hi = row_start[node + 1];
    for (int i = lo; i < hi; ++i) {
        int s = elist[i];
        float4 v = h4[s * 64 + lane];
        acc.x += v.x; acc.y += v.y; acc.z += v.z; acc.w += v.w;
    }
    ((float4*)z0)[node * 64 + lane] = acc;
}

// C = relu(A @ W + bias), A: [M,256], W: [256,256] row-major, tile 64x64, 4x4/thread
#define BM 64
#define BN 64
#define BK 16
__global__ __launch_bounds__(256) void k_gemm(const float* __restrict__ A,
                                              const float* __restrict__ W,
                                              const float* __restrict__ bias,
                                              float* __restrict__ C, int M) {
    __shared__ float As[BK][BM + 4];
    __shared__ float Bs[BK][BN + 4];
    int tid = threadIdx.x;
    int tx = tid & 15, ty = tid >> 4;
    int m0 = blockIdx.x * BM;
    int n0 = blockIdx.y * BN;
    float acc[4][4] = {};

    for (int k0 = 0; k0 < DD; k0 += BK) {
        // A tile: 64 rows x 16 k  (16 tids per row-group, 4 row passes)
        {
            int col = tid & 15;
            int row0 = tid >> 4;
            #pragma unroll
            for (int r = row0; r < BM; r += 16) {
                int gr = m0 + r;
                As[col][r] = (gr < M) ? A[gr * DD + k0 + col] : 0.f;
            }
            // B tile: 16 k x 64 n
            int nc = tid & 63;
            int kr = tid >> 6;
            #pragma unroll
            for (int r = kr; r < BK; r += 4) {
                Bs[r][nc] = W[(k0 + r) * DD + n0 + nc];
            }
        }
        __syncthreads();
        #pragma unroll
        for (int kk = 0; kk < BK; ++kk) {
            float4 a = *(const float4*)&As[kk][ty * 4];
            float4 b = *(const float4*)&Bs[kk][tx * 4];
            float av[4] = {a.x, a.y, a.z, a.w};
            float bv[4] = {b.x, b.y, b.z, b.w};
            #pragma unroll
            for (int i = 0; i < 4; ++i)
                #pragma unroll
                for (int j = 0; j < 4; ++j)
                    acc[i][j] += av[i] * bv[j];
        }
        __syncthreads();
    }

    #pragma unroll
    for (int i = 0; i < 4; ++i) {
        int gr = m0 + ty * 4 + i;
        if (gr >= M) continue;
        float4 o;
        float* op = &o.x;
        #pragma unroll
        for (int j = 0; j < 4; ++j) {
            float v = acc[i][j] + bias[n0 + tx * 4 + j];
            op[j] = v > 0.f ? v : 0.f;
        }
        *(float4*)&C[gr * DD + n0 + tx * 4] = o;
    }
}

// column sum / sumsq with per-block register accumulation + one atomic per column
__global__ __launch_bounds__(256) void k_bnstats(const float* __restrict__ z,
                                                 float* __restrict__ sums) {
    int col = threadIdx.x;
    float s = 0.f, s2 = 0.f;
    for (int r = blockIdx.x; r < NN; r += gridDim.x) {
        float v = z[r * DD + col];
        s += v; s2 += v * v;
    }
    atomicAdd(&sums[col], s);
    atomicAdd(&sums[DD + col], s2);
}

__global__ void k_bnscale(const float* __restrict__ sums, const float* __restrict__ gamma,
                          const float* __restrict__ beta, float* __restrict__ ss) {
    int c = threadIdx.x;
    float mean = sums[c] * (1.0f / NN);
    float var = sums[DD + c] * (1.0f / NN) - mean * mean;
    float sc = gamma[c] * rsqrtf(var + BN_EPS);
    ss[c] = sc;
    ss[DD + c] = beta[c] - mean * sc;
}

__global__ void k_bnapply(float* __restrict__ z, const float* __restrict__ ss) {
    int idx = blockIdx.x * blockDim.x + threadIdx.x;
    const int total4 = NN * DD / 4;
    const float4* sc4 = (const float4*)ss;
    const float4* sh4 = (const float4*)(ss + DD);
    float4* z4 = (float4*)z;
    for (int i = idx; i < total4; i += gridDim.x * blockDim.x) {
        int c = i & 63;
        float4 v = z4[i];
        float4 s = sc4[c];
        float4 b = sh4[c];
        v.x = v.x * s.x + b.x;
        v.y = v.y * s.y + b.y;
        v.z = v.z * s.z + b.z;
        v.w = v.w * s.w + b.w;
        z4[i] = v;
    }
}

// per-graph sum over contiguous (sorted-batch) node ranges
__global__ __launch_bounds__(256) void k_pool(const float* __restrict__ z,
                                              const int* __restrict__ gstart,
                                              float* __restrict__ out, int layer) {
    int g = blockIdx.x, c = threadIdx.x;
    float s = 0.f;
    int lo = gstart[g], hi = gstart[g + 1];
    for (int r = lo; r < hi; ++r) s += z[r * DD + c];
    out[g * (NL * DD) + layer * DD + c] = s;
}

extern "C" void kernel_launch(void* const* d_in, const int* in_sizes, int n_in,
                              void* d_out, int out_size, void* d_ws, size_t ws_size,
                              hipStream_t stream) {
    const float* x     = (const float*)d_in[0];
    const int*   ei    = (const int*)d_in[1];
    const int*   batch = (const int*)d_in[2];
    const float* w1    = (const float*)d_in[3];
    const float* b1    = (const float*)d_in[4];
    const float* w2    = (const float*)d_in[5];
    const float* b2    = (const float*)d_in[6];
    const float* gamma = (const float*)d_in[7];
    const float* beta  = (const float*)d_in[8];
    float* out = (float*)d_out;

    char* ws = (char*)d_ws;
    size_t off = 0;
    auto alloc = [&](size_t bytes) -> void* {
        void* p = ws + off;
        off += (bytes + 255) & ~size_t(255);
        return p;
    };
    float* buf0 = (float*)alloc((size_t)NN * DD * 4);
    float* buf1 = (float*)alloc((size_t)NN * DD * 4);
    float* buf2 = (float*)alloc((size_t)NN * DD * 4);
    int* deg       = (int*)alloc((size_t)NN * 4);
    int* row_start = (int*)alloc((size_t)(NN + 1) * 4);
    int* cursor    = (int*)alloc((size_t)NN * 4);
    int* elist     = (int*)alloc((size_t)NE * 4);
    int* gcount    = (int*)alloc((size_t)NG * 4);
    int* gstart    = (int*)alloc((size_t)(NG + 1) * 4);
    float* sums    = (float*)alloc(2 * DD * 4);
    float* ss      = (float*)alloc(2 * DD * 4);

    // CSR + graph boundaries (rebuilt every call — deterministic inputs)
    k_zero<<<(NN + 255) / 256, 256, 0, stream>>>(deg, NN);
    k_zero<<<1, 256, 0, stream>>>(gcount, NG);
    k_count<<<(NE + 255) / 256, 256, 0, stream>>>(ei, deg, gcount, batch);
    k_scan<<<1, 256, 0, stream>>>(deg, row_start, cursor, NN);
    k_scan<<<1, 256, 0, stream>>>(gcount, gstart, nullptr, NG);
    k_scatter<<<(NE + 255) / 256, 256, 0, stream>>>(ei, cursor, elist);

    dim3 ggrid((NN + BM - 1) / BM, DD / BN);
    for (int l = 0; l < NL; ++l) {
        const float* h = (l == 0) ? x : buf0;
        k_agg<<<NN, 64, 0, stream>>>(h, row_start, elist, buf1);
        k_gemm<<<ggrid, 256, 0, stream>>>(buf1, w1 + (size_t)l * DD * DD, b1 + l * DD, buf2, NN);
        k_gemm<<<ggrid, 256, 0, stream>>>(buf2, w2 + (size_t)l * DD * DD, b2 + l * DD, buf0, NN);
        k_zero<<<2, 256, 0, stream>>>((int*)sums, 2 * DD);
        k_bnstats<<<400, 256, 0, stream>>>(buf0, sums);
        k_bnscale<<<1, 256, 0, stream>>>(sums, gamma + l * DD, beta + l * DD, ss);
        k_bnapply<<<1024, 256, 0, stream>>>(buf0, ss);
        k_pool<<<NG, 256, 0, stream>>>(buf0, gstart, out, l);
    }
}

// Round 2
// 955.531 us; speedup vs baseline: 1.7546x; 1.7546x over previous
//
#include <hip/hip_runtime.h>

#define NN 50000
#define NE 800000
#define NG 256
#define DD 256
#define NL 3
#define BN_EPS 1e-5f
#define MPAD 50048   // 391 * 128

typedef short bf16x8 __attribute__((ext_vector_type(8)));
typedef float f32x4 __attribute__((ext_vector_type(4)));

__device__ __forceinline__ unsigned short f2bf(float f) {
    unsigned int u = __float_as_uint(f);
    u += 0x7FFFu + ((u >> 16) & 1u);
    return (unsigned short)(u >> 16);
}
__device__ __forceinline__ float bf2f(unsigned short s) {
    return __uint_as_float(((unsigned int)s) << 16);
}

// ---------- CSR build ----------
__global__ void k_zero(int* p, int n) {
    int i = blockIdx.x * blockDim.x + threadIdx.x;
    if (i < n) p[i] = 0;
}

__global__ void k_count(const int* __restrict__ ei, int* __restrict__ deg,
                        int* __restrict__ gcount, const int* __restrict__ batch) {
    int e = blockIdx.x * blockDim.x + threadIdx.x;
    if (e < NE) atomicAdd(&deg[ei[NE + e]], 1);
    if (e < NN) atomicAdd(&gcount[batch[e]], 1);
}

__global__ void k_scan(const int* __restrict__ in, int* __restrict__ out,
                       int* __restrict__ cursor, int n) {
    __shared__ int tsum[256];
    int t = threadIdx.x;
    int chunk = (n + 255) / 256;
    int lo = t * chunk;
    int hi = min(lo + chunk, n);
    int s = 0;
    for (int i = lo; i < hi; ++i) s += in[i];
    tsum[t] = s;
    __syncthreads();
    if (t == 0) {
        int acc = 0;
        for (int i = 0; i < 256; ++i) { int v = tsum[i]; tsum[i] = acc; acc += v; }
    }
    __syncthreads();
    int acc = tsum[t];
    for (int i = lo; i < hi; ++i) {
        out[i] = acc;
        if (cursor) cursor[i] = acc;
        acc += in[i];
    }
    if (hi == n) out[n] = acc;
}

__global__ void k_scatter(const int* __restrict__ ei, int* __restrict__ cursor,
                          int* __restrict__ elist) {
    int e = blockIdx.x * blockDim.x + threadIdx.x;
    if (e >= NE) return;
    int s = ei[e];
    int d = ei[NE + e];
    int pos = atomicAdd(&cursor[d], 1);
    elist[pos] = s;
}

// ---------- conversions ----------
__global__ void k_f2bf(const float* __restrict__ in, unsigned short* __restrict__ out, int n4) {
    int i = blockIdx.x * blockDim.x + threadIdx.x;
    if (i >= n4) return;
    float4 v = ((const float4*)in)[i];
    ushort4 o;
    o.x = f2bf(v.x); o.y = f2bf(v.y); o.z = f2bf(v.z); o.w = f2bf(v.w);
    ((ushort4*)out)[i] = o;
}

__global__ void k_zpad(unsigned short* p) {
    int i = blockIdx.x * blockDim.x + threadIdx.x;
    const int total = (MPAD - NN) * DD;
    if (i < total) p[NN * DD + i] = 0;
}

// wt[mat][n][k] = w[mat][k][n] as bf16; mats 0..2 = w1 layers, 3..5 = w2 layers
__global__ void k_wconv(const float* __restrict__ w1, const float* __restrict__ w2,
                        unsigned short* __restrict__ wt) {
    int flat = blockIdx.x * blockDim.x + threadIdx.x;
    if (flat >= 6 * 65536) return;
    int mat = flat >> 16;
    int n = (flat >> 8) & 255;
    int k = flat & 255;
    const float* src = (mat < 3) ? (w1 + ((size_t)mat << 16)) : (w2 + ((size_t)(mat - 3) << 16));
    wt[flat] = f2bf(src[k * 256 + n]);
}

// ---------- aggregation: z0 = h + sum_{src} h[src], bf16 in/out, fp32 accum ----------
__global__ __launch_bounds__(64) void k_agg_bf(const unsigned short* __restrict__ h,
                                               const int* __restrict__ row_start,
                                               const int* __restrict__ elist,
                                               unsigned short* __restrict__ z0) {
    int node = blockIdx.x;
    int lane = threadIdx.x;
    const ushort4* h4 = (const ushort4*)h;
    ushort4 own = h4[node * 64 + lane];
    float a0 = bf2f(own.x), a1 = bf2f(own.y), a2 = bf2f(own.z), a3 = bf2f(own.w);
    int lo = row_start[node], hi = row_start[node + 1];
    for (int i = lo; i < hi; ++i) {
        int s = elist[i];
        ushort4 v = h4[s * 64 + lane];
        a0 += bf2f(v.x); a1 += bf2f(v.y); a2 += bf2f(v.z); a3 += bf2f(v.w);
    }
    ushort4 o;
    o.x = f2bf(a0); o.y = f2bf(a1); o.z = f2bf(a2); o.w = f2bf(a3);
    ((ushort4*)z0)[node * 64 + lane] = o;
}

// ---------- bf16 MFMA GEMM: C = relu(A @ W + bias) ----------
// A: [MPAD,256] bf16 row-major. BT: [256,256] bf16, BT[n][k] = W[k][n].
// 128x128 tile, 4 waves (2x2), each wave 64x64 via 4x4 frags of 16x16x32.
#define GBM 128
#define GBK 64
template<int OUT_BF16>
__global__ __launch_bounds__(256) void k_mfma_gemm(const unsigned short* __restrict__ A,
                                                   const unsigned short* __restrict__ BT,
                                                   const float* __restrict__ bias,
                                                   void* __restrict__ Cout) {
    __shared__ short As[GBM * GBK];
    __shared__ short Bs[GBM * GBK];
    int tid = threadIdx.x;
    int lane = tid & 63;
    int wave = tid >> 6;
    int wr = wave >> 1, wc = wave & 1;
    long m0 = (long)blockIdx.x * GBM;
    int n0 = blockIdx.y * GBM;
    const int r = lane & 15, hi = lane >> 4;

    f32x4 acc[4][4];
    #pragma unroll
    for (int m = 0; m < 4; ++m)
        #pragma unroll
        for (int n = 0; n < 4; ++n)
            acc[m][n] = (f32x4){0.f, 0.f, 0.f, 0.f};

    for (int k0 = 0; k0 < DD; k0 += GBK) {
        // stage A,B tiles: 128 rows x 64 k each, 16B chunks, XOR-swizzled slots
        #pragma unroll
        for (int p = 0; p < 4; ++p) {
            int flat = p * 256 + tid;       // 0..1023
            int row = flat >> 3;
            int c8 = flat & 7;
            int slot = c8 ^ (row & 7);
            bf16x8 va = *(const bf16x8*)(A + (m0 + row) * DD + k0 + c8 * 8);
            *(bf16x8*)(As + row * GBK + slot * 8) = va;
            bf16x8 vb = *(const bf16x8*)(BT + (long)(n0 + row) * DD + k0 + c8 * 8);
            *(bf16x8*)(Bs + row * GBK + slot * 8) = vb;
        }
        __syncthreads();

        bf16x8 af[4][2], bfr[4][2];
        #pragma unroll
        for (int m = 0; m < 4; ++m) {
            int row = wr * 64 + m * 16 + r;
            #pragma unroll
            for (int kk = 0; kk < 2; ++kk) {
                int slot = (kk * 4 + hi) ^ (row & 7);
                af[m][kk] = *(const bf16x8*)(As + row * GBK + slot * 8);
            }
        }
        #pragma unroll
        for (int n = 0; n < 4; ++n) {
            int col = wc * 64 + n * 16 + r;
            #pragma unroll
            for (int kk = 0; kk < 2; ++kk) {
                int slot = (kk * 4 + hi) ^ (col & 7);
                bfr[n][kk] = *(const bf16x8*)(Bs + col * GBK + slot * 8);
            }
        }
        #pragma unroll
        for (int kk = 0; kk < 2; ++kk)
            #pragma unroll
            for (int m = 0; m < 4; ++m)
                #pragma unroll
                for (int n = 0; n < 4; ++n)
                    acc[m][n] = __builtin_amdgcn_mfma_f32_16x16x32_bf16(af[m][kk], bfr[n][kk], acc[m][n], 0, 0, 0);
        __syncthreads();
    }

    // epilogue: bias + relu, C/D layout col=lane&15, row=(lane>>4)*4+reg
    #pragma unroll
    for (int n = 0; n < 4; ++n) {
        int col = n0 + wc * 64 + n * 16 + r;
        float bv = bias[col];
        #pragma unroll
        for (int m = 0; m < 4; ++m) {
            #pragma unroll
            for (int j = 0; j < 4; ++j) {
                long grow = m0 + wr * 64 + m * 16 + hi * 4 + j;
                float v = acc[m][n][j] + bv;
                v = v > 0.f ? v : 0.f;
                if (OUT_BF16) ((unsigned short*)Cout)[grow * DD + col] = f2bf(v);
                else          ((float*)Cout)[grow * DD + col] = v;
            }
        }
    }
}

// ---------- BN ----------
__global__ __launch_bounds__(256) void k_bnstats(const float* __restrict__ z,
                                                 float* __restrict__ sums) {
    int col = threadIdx.x;
    float s = 0.f, s2 = 0.f;
    for (int r = blockIdx.x; r < NN; r += gridDim.x) {
        float v = z[r * DD + col];
        s += v; s2 += v * v;
    }
    atomicAdd(&sums[col], s);
    atomicAdd(&sums[DD + col], s2);
}

__global__ void k_bnscale(const float* __restrict__ sums, const float* __restrict__ gamma,
                          const float* __restrict__ beta, float* __restrict__ ss) {
    int c = threadIdx.x;
    float mean = sums[c] * (1.0f / NN);
    float var = sums[DD + c] * (1.0f / NN) - mean * mean;
    float sc = gamma[c] * rsqrtf(var + BN_EPS);
    ss[c] = sc;
    ss[DD + c] = beta[c] - mean * sc;
}

// z = z*scale+shift (fp32, in place) and also emit bf16 copy for next layer's agg
__global__ void k_bnapply(float* __restrict__ z, const float* __restrict__ ss,
                          unsigned short* __restrict__ hbf) {
    int idx = blockIdx.x * blockDim.x + threadIdx.x;
    const int total4 = NN * DD / 4;
    const float4* sc4 = (const float4*)ss;
    const float4* sh4 = (const float4*)(ss + DD);
    float4* z4 = (float4*)z;
    ushort4* h4 = (ushort4*)hbf;
    for (int i = idx; i < total4; i += gridDim.x * blockDim.x) {
        int c = i & 63;
        float4 v = z4[i];
        float4 s = sc4[c];
        float4 b = sh4[c];
        v.x = v.x * s.x + b.x;
        v.y = v.y * s.y + b.y;
        v.z = v.z * s.z + b.z;
        v.w = v.w * s.w + b.w;
        z4[i] = v;
        ushort4 o;
        o.x = f2bf(v.x); o.y = f2bf(v.y); o.z = f2bf(v.z); o.w = f2bf(v.w);
        h4[i] = o;
    }
}

__global__ __launch_bounds__(256) void k_pool(const float* __restrict__ z,
                                              const int* __restrict__ gstart,
                                              float* __restrict__ out, int layer) {
    int g = blockIdx.x, c = threadIdx.x;
    float s = 0.f;
    int lo = gstart[g], hi = gstart[g + 1];
    for (int r = lo; r < hi; ++r) s += z[r * DD + c];
    out[g * (NL * DD) + layer * DD + c] = s;
}

extern "C" void kernel_launch(void* const* d_in, const int* in_sizes, int n_in,
                              void* d_out, int out_size, void* d_ws, size_t ws_size,
                              hipStream_t stream) {
    const float* x     = (const float*)d_in[0];
    const int*   ei    = (const int*)d_in[1];
    const int*   batch = (const int*)d_in[2];
    const float* w1    = (const float*)d_in[3];
    const float* b1    = (const float*)d_in[4];
    const float* w2    = (const float*)d_in[5];
    const float* b2    = (const float*)d_in[6];
    const float* gamma = (const float*)d_in[7];
    const float* beta  = (const float*)d_in[8];
    float* out = (float*)d_out;

    char* ws = (char*)d_ws;
    size_t off = 0;
    auto alloc = [&](size_t bytes) -> void* {
        void* p = ws + off;
        off += (bytes + 255) & ~size_t(255);
        return p;
    };
    float*          buf0 = (float*)alloc((size_t)MPAD * DD * 4);          // fp32 GEMM2 out / BN
    unsigned short* zbf  = (unsigned short*)alloc((size_t)MPAD * DD * 2); // agg out (GEMM1 A)
    unsigned short* h1bf = (unsigned short*)alloc((size_t)MPAD * DD * 2); // GEMM1 out (GEMM2 A)
    unsigned short* hbf  = (unsigned short*)alloc((size_t)NN * DD * 2);   // h as bf16
    unsigned short* wt   = (unsigned short*)alloc((size_t)6 * DD * DD * 2);
    int* deg       = (int*)alloc((size_t)NN * 4);
    int* row_start = (int*)alloc((size_t)(NN + 1) * 4);
    int* cursor    = (int*)alloc((size_t)NN * 4);
    int* elist     = (int*)alloc((size_t)NE * 4);
    int* gcount    = (int*)alloc((size_t)NG * 4);
    int* gstart    = (int*)alloc((size_t)(NG + 1) * 4);
    float* sums    = (float*)alloc(2 * DD * 4);
    float* ss      = (float*)alloc(2 * DD * 4);

    // CSR + graph boundaries
    k_zero<<<(NN + 255) / 256, 256, 0, stream>>>(deg, NN);
    k_zero<<<1, 256, 0, stream>>>(gcount, NG);
    k_count<<<(NE + 255) / 256, 256, 0, stream>>>(ei, deg, gcount, batch);
    k_scan<<<1, 256, 0, stream>>>(deg, row_start, cursor, NN);
    k_scan<<<1, 256, 0, stream>>>(gcount, gstart, nullptr, NG);
    k_scatter<<<(NE + 255) / 256, 256, 0, stream>>>(ei, cursor, elist);

    // weight transpose+convert, x -> bf16, zero pad rows of zbf
    k_wconv<<<(6 * 65536 + 255) / 256, 256, 0, stream>>>(w1, w2, wt);
    k_f2bf<<<(NN * DD / 4 + 255) / 256, 256, 0, stream>>>(x, hbf, NN * DD / 4);
    k_zpad<<<((MPAD - NN) * DD + 255) / 256, 256, 0, stream>>>(zbf);

    dim3 ggrid(MPAD / GBM, DD / GBM);
    for (int l = 0; l < NL; ++l) {
        k_agg_bf<<<NN, 64, 0, stream>>>(hbf, row_start, elist, zbf);
        k_mfma_gemm<1><<<ggrid, 256, 0, stream>>>(zbf, wt + (size_t)l * DD * DD, b1 + l * DD, h1bf);
        k_mfma_gemm<0><<<ggrid, 256, 0, stream>>>(h1bf, wt + (size_t)(3 + l) * DD * DD, b2 + l * DD, buf0);
        k_zero<<<2, 256, 0, stream>>>((int*)sums, 2 * DD);
        k_bnstats<<<400, 256, 0, stream>>>(buf0, sums);
        k_bnscale<<<1, 256, 0, stream>>>(sums, gamma + l * DD, beta + l * DD, ss);
        k_bnapply<<<1024, 256, 0, stream>>>(buf0, ss, hbf);
        k_pool<<<NG, 256, 0, stream>>>(buf0, gstart, out, l);
    }
}

// Round 3
// 787.885 us; speedup vs baseline: 2.1280x; 1.2128x over previous
//
#include <hip/hip_runtime.h>

#define NN 50000
#define NE 800000
#define NG 256
#define DD 256
#define NL 3
#define BN_EPS 1e-5f
#define MPAD 50048   // 391 * 128
#define NBLK 196     // ceil(NN/256)

typedef short bf16x8 __attribute__((ext_vector_type(8)));
typedef float f32x4 __attribute__((ext_vector_type(4)));

__device__ __forceinline__ unsigned short f2bf(float f) {
    unsigned int u = __float_as_uint(f);
    u += 0x7FFFu + ((u >> 16) & 1u);
    return (unsigned short)(u >> 16);
}
__device__ __forceinline__ float bf2f(unsigned short s) {
    return __uint_as_float(((unsigned int)s) << 16);
}

// ---------- init: zero deg, gcount, sums ----------
__global__ void k_init(int* __restrict__ deg, int* __restrict__ gcount,
                       float* __restrict__ sums) {
    int i = blockIdx.x * blockDim.x + threadIdx.x;
    if (i < NN) deg[i] = 0;
    if (i < NG) gcount[i] = 0;
    if (i < 2 * DD) sums[i] = 0.f;
}

__global__ void k_count(const int* __restrict__ ei, int* __restrict__ deg,
                        int* __restrict__ gcount, const int* __restrict__ batch) {
    int e = blockIdx.x * blockDim.x + threadIdx.x;
    if (e < NE) atomicAdd(&deg[ei[NE + e]], 1);
    if (e < NN) atomicAdd(&gcount[batch[e]], 1);
}

// ---------- hierarchical scan ----------
// stage 1: per-block sums of deg
__global__ __launch_bounds__(256) void k_scan1(const int* __restrict__ deg,
                                               int* __restrict__ bsum) {
    __shared__ int red[256];
    int t = threadIdx.x;
    int i = blockIdx.x * 256 + t;
    red[t] = (i < NN) ? deg[i] : 0;
    __syncthreads();
    #pragma unroll
    for (int d = 128; d > 0; d >>= 1) {
        if (t < d) red[t] += red[t + d];
        __syncthreads();
    }
    if (t == 0) bsum[blockIdx.x] = red[0];
}

// stage 2: exclusive scan of block sums (nb <= 256), single block
__global__ __launch_bounds__(256) void k_scan2(const int* __restrict__ bsum,
                                               int* __restrict__ boff, int nb) {
    __shared__ int s[256];
    int t = threadIdx.x;
    int v = (t < nb) ? bsum[t] : 0;
    s[t] = v;
    __syncthreads();
    #pragma unroll
    for (int d = 1; d < 256; d <<= 1) {
        int add = (t >= d) ? s[t - d] : 0;
        __syncthreads();
        s[t] += add;
        __syncthreads();
    }
    boff[t] = s[t] - v;   // exclusive
}

// stage 3: per-block local exclusive scan + block offset -> row_start, cursor
__global__ __launch_bounds__(256) void k_scan3(const int* __restrict__ deg,
                                               const int* __restrict__ boff,
                                               int* __restrict__ row_start,
                                               int* __restrict__ cursor) {
    __shared__ int s[256];
    int t = threadIdx.x;
    int i = blockIdx.x * 256 + t;
    int v = (i < NN) ? deg[i] : 0;
    s[t] = v;
    __syncthreads();
    #pragma unroll
    for (int d = 1; d < 256; d <<= 1) {
        int add = (t >= d) ? s[t - d] : 0;
        __syncthreads();
        s[t] += add;
        __syncthreads();
    }
    int excl = boff[blockIdx.x] + s[t] - v;
    if (i < NN) { row_start[i] = excl; cursor[i] = excl; }
    if (blockIdx.x == 0 && t == 0) row_start[NN] = NE;
}

// graph boundaries: exclusive scan of gcount (exactly 256 entries), single block
__global__ __launch_bounds__(256) void k_scan_g(const int* __restrict__ gcount,
                                                int* __restrict__ gstart) {
    __shared__ int s[256];
    int t = threadIdx.x;
    int v = gcount[t];
    s[t] = v;
    __syncthreads();
    #pragma unroll
    for (int d = 1; d < 256; d <<= 1) {
        int add = (t >= d) ? s[t - d] : 0;
        __syncthreads();
        s[t] += add;
        __syncthreads();
    }
    gstart[t] = s[t] - v;
    if (t == 0) gstart[NG] = NN;
}

__global__ void k_scatter(const int* __restrict__ ei, int* __restrict__ cursor,
                          int* __restrict__ elist) {
    int e = blockIdx.x * blockDim.x + threadIdx.x;
    if (e >= NE) return;
    int s = ei[e];
    int d = ei[NE + e];
    int pos = atomicAdd(&cursor[d], 1);
    elist[pos] = s;
}

// ---------- conversions ----------
__global__ void k_f2bf(const float* __restrict__ in, unsigned short* __restrict__ out, int n4) {
    int i = blockIdx.x * blockDim.x + threadIdx.x;
    if (i >= n4) return;
    float4 v = ((const float4*)in)[i];
    ushort4 o;
    o.x = f2bf(v.x); o.y = f2bf(v.y); o.z = f2bf(v.z); o.w = f2bf(v.w);
    ((ushort4*)out)[i] = o;
}

__global__ void k_zpad(unsigned short* p) {
    int i = blockIdx.x * blockDim.x + threadIdx.x;
    const int total = (MPAD - NN) * DD;
    if (i < total) p[NN * DD + i] = 0;
}

// wt[mat][n][k] = w[mat][k][n] as bf16; mats 0..2 = w1 layers, 3..5 = w2 layers
__global__ void k_wconv(const float* __restrict__ w1, const float* __restrict__ w2,
                        unsigned short* __restrict__ wt) {
    int flat = blockIdx.x * blockDim.x + threadIdx.x;
    if (flat >= 6 * 65536) return;
    int mat = flat >> 16;
    int n = (flat >> 8) & 255;
    int k = flat & 255;
    const float* src = (mat < 3) ? (w1 + ((size_t)mat << 16)) : (w2 + ((size_t)(mat - 3) << 16));
    wt[flat] = f2bf(src[k * 256 + n]);
}

// ---------- aggregation: z0 = h + sum_{src} h[src], bf16 in/out, fp32 accum ----------
__global__ __launch_bounds__(64) void k_agg_bf(const unsigned short* __restrict__ h,
                                               const int* __restrict__ row_start,
                                               const int* __restrict__ elist,
                                               unsigned short* __restrict__ z0) {
    int node = blockIdx.x;
    int lane = threadIdx.x;
    const ushort4* h4 = (const ushort4*)h;
    ushort4 own = h4[node * 64 + lane];
    float a0 = bf2f(own.x), a1 = bf2f(own.y), a2 = bf2f(own.z), a3 = bf2f(own.w);
    int lo = row_start[node], hi = row_start[node + 1];
    for (int i = lo; i < hi; ++i) {
        int s = elist[i];
        ushort4 v = h4[s * 64 + lane];
        a0 += bf2f(v.x); a1 += bf2f(v.y); a2 += bf2f(v.z); a3 += bf2f(v.w);
    }
    ushort4 o;
    o.x = f2bf(a0); o.y = f2bf(a1); o.z = f2bf(a2); o.w = f2bf(a3);
    ((ushort4*)z0)[node * 64 + lane] = o;
}

// ---------- bf16 MFMA GEMM: C = relu(A @ W + bias) ----------
#define GBM 128
#define GBK 64
template<int OUT_BF16>
__global__ __launch_bounds__(256) void k_mfma_gemm(const unsigned short* __restrict__ A,
                                                   const unsigned short* __restrict__ BT,
                                                   const float* __restrict__ bias,
                                                   void* __restrict__ Cout) {
    __shared__ short As[GBM * GBK];
    __shared__ short Bs[GBM * GBK];
    int tid = threadIdx.x;
    int lane = tid & 63;
    int wave = tid >> 6;
    int wr = wave >> 1, wc = wave & 1;
    long m0 = (long)blockIdx.x * GBM;
    int n0 = blockIdx.y * GBM;
    const int r = lane & 15, hi = lane >> 4;

    f32x4 acc[4][4];
    #pragma unroll
    for (int m = 0; m < 4; ++m)
        #pragma unroll
        for (int n = 0; n < 4; ++n)
            acc[m][n] = (f32x4){0.f, 0.f, 0.f, 0.f};

    for (int k0 = 0; k0 < DD; k0 += GBK) {
        #pragma unroll
        for (int p = 0; p < 4; ++p) {
            int flat = p * 256 + tid;
            int row = flat >> 3;
            int c8 = flat & 7;
            int slot = c8 ^ (row & 7);
            bf16x8 va = *(const bf16x8*)(A + (m0 + row) * DD + k0 + c8 * 8);
            *(bf16x8*)(As + row * GBK + slot * 8) = va;
            bf16x8 vb = *(const bf16x8*)(BT + (long)(n0 + row) * DD + k0 + c8 * 8);
            *(bf16x8*)(Bs + row * GBK + slot * 8) = vb;
        }
        __syncthreads();

        bf16x8 af[4][2], bfr[4][2];
        #pragma unroll
        for (int m = 0; m < 4; ++m) {
            int row = wr * 64 + m * 16 + r;
            #pragma unroll
            for (int kk = 0; kk < 2; ++kk) {
                int slot = (kk * 4 + hi) ^ (row & 7);
                af[m][kk] = *(const bf16x8*)(As + row * GBK + slot * 8);
            }
        }
        #pragma unroll
        for (int n = 0; n < 4; ++n) {
            int col = wc * 64 + n * 16 + r;
            #pragma unroll
            for (int kk = 0; kk < 2; ++kk) {
                int slot = (kk * 4 + hi) ^ (col & 7);
                bfr[n][kk] = *(const bf16x8*)(Bs + col * GBK + slot * 8);
            }
        }
        #pragma unroll
        for (int kk = 0; kk < 2; ++kk)
            #pragma unroll
            for (int m = 0; m < 4; ++m)
                #pragma unroll
                for (int n = 0; n < 4; ++n)
                    acc[m][n] = __builtin_amdgcn_mfma_f32_16x16x32_bf16(af[m][kk], bfr[n][kk], acc[m][n], 0, 0, 0);
        __syncthreads();
    }

    #pragma unroll
    for (int n = 0; n < 4; ++n) {
        int col = n0 + wc * 64 + n * 16 + r;
        float bv = bias[col];
        #pragma unroll
        for (int m = 0; m < 4; ++m) {
            #pragma unroll
            for (int j = 0; j < 4; ++j) {
                long grow = m0 + wr * 64 + m * 16 + hi * 4 + j;
                float v = acc[m][n][j] + bv;
                v = v > 0.f ? v : 0.f;
                if (OUT_BF16) ((unsigned short*)Cout)[grow * DD + col] = f2bf(v);
                else          ((float*)Cout)[grow * DD + col] = v;
            }
        }
    }
}

// ---------- BN ----------
__global__ __launch_bounds__(256) void k_bnstats(const float* __restrict__ z,
                                                 float* __restrict__ sums) {
    int col = threadIdx.x;
    float s = 0.f, s2 = 0.f;
    for (int r = blockIdx.x; r < NN; r += gridDim.x) {
        float v = z[r * DD + col];
        s += v; s2 += v * v;
    }
    atomicAdd(&sums[col], s);
    atomicAdd(&sums[DD + col], s2);
}

// compute scale/shift, then re-zero sums for the next layer's bnstats
__global__ void k_bnscale(float* __restrict__ sums, const float* __restrict__ gamma,
                          const float* __restrict__ beta, float* __restrict__ ss) {
    int c = threadIdx.x;
    float mean = sums[c] * (1.0f / NN);
    float var = sums[DD + c] * (1.0f / NN) - mean * mean;
    float sc = gamma[c] * rsqrtf(var + BN_EPS);
    ss[c] = sc;
    ss[DD + c] = beta[c] - mean * sc;
    sums[c] = 0.f;
    sums[DD + c] = 0.f;
}

// fused BN-apply + bf16 emit + global_add_pool (one block per graph)
__global__ __launch_bounds__(256) void k_bnpool(const float* __restrict__ z,
                                                const float* __restrict__ ss,
                                                const int* __restrict__ gstart,
                                                unsigned short* __restrict__ hbf,
                                                float* __restrict__ out, int layer) {
    int g = blockIdx.x, c = threadIdx.x;
    float sc = ss[c];
    float sh = ss[DD + c];
    int lo = gstart[g], hi = gstart[g + 1];
    float s = 0.f;
    for (int r = lo; r < hi; ++r) {
        float v = z[r * DD + c] * sc + sh;
        s += v;
        hbf[r * DD + c] = f2bf(v);
    }
    out[g * (NL * DD) + layer * DD + c] = s;
}

extern "C" void kernel_launch(void* const* d_in, const int* in_sizes, int n_in,
                              void* d_out, int out_size, void* d_ws, size_t ws_size,
                              hipStream_t stream) {
    const float* x     = (const float*)d_in[0];
    const int*   ei    = (const int*)d_in[1];
    const int*   batch = (const int*)d_in[2];
    const float* w1    = (const float*)d_in[3];
    const float* b1    = (const float*)d_in[4];
    const float* w2    = (const float*)d_in[5];
    const float* b2    = (const float*)d_in[6];
    const float* gamma = (const float*)d_in[7];
    const float* beta  = (const float*)d_in[8];
    float* out = (float*)d_out;

    char* ws = (char*)d_ws;
    size_t off = 0;
    auto alloc = [&](size_t bytes) -> void* {
        void* p = ws + off;
        off += (bytes + 255) & ~size_t(255);
        return p;
    };
    float*          buf0 = (float*)alloc((size_t)MPAD * DD * 4);          // fp32 GEMM2 out
    unsigned short* zbf  = (unsigned short*)alloc((size_t)MPAD * DD * 2); // agg out (GEMM1 A)
    unsigned short* h1bf = (unsigned short*)alloc((size_t)MPAD * DD * 2); // GEMM1 out (GEMM2 A)
    unsigned short* hbf  = (unsigned short*)alloc((size_t)NN * DD * 2);   // h as bf16
    unsigned short* wt   = (unsigned short*)alloc((size_t)6 * DD * DD * 2);
    int* deg       = (int*)alloc((size_t)NN * 4);
    int* row_start = (int*)alloc((size_t)(NN + 1) * 4);
    int* cursor    = (int*)alloc((size_t)NN * 4);
    int* elist     = (int*)alloc((size_t)NE * 4);
    int* gcount    = (int*)alloc((size_t)NG * 4);
    int* gstart    = (int*)alloc((size_t)(NG + 1) * 4);
    int* bsum      = (int*)alloc(256 * 4);
    int* boff      = (int*)alloc(256 * 4);
    float* sums    = (float*)alloc(2 * DD * 4);
    float* ss      = (float*)alloc(2 * DD * 4);

    // CSR + graph boundaries (parallel scan)
    k_init<<<NBLK, 256, 0, stream>>>(deg, gcount, sums);
    k_count<<<(NE + 255) / 256, 256, 0, stream>>>(ei, deg, gcount, batch);
    k_scan1<<<NBLK, 256, 0, stream>>>(deg, bsum);
    k_scan2<<<1, 256, 0, stream>>>(bsum, boff, NBLK);
    k_scan3<<<NBLK, 256, 0, stream>>>(deg, boff, row_start, cursor);
    k_scan_g<<<1, 256, 0, stream>>>(gcount, gstart);
    k_scatter<<<(NE + 255) / 256, 256, 0, stream>>>(ei, cursor, elist);

    // weight transpose+convert, x -> bf16, zero pad rows of zbf
    k_wconv<<<(6 * 65536 + 255) / 256, 256, 0, stream>>>(w1, w2, wt);
    k_f2bf<<<(NN * DD / 4 + 255) / 256, 256, 0, stream>>>(x, hbf, NN * DD / 4);
    k_zpad<<<((MPAD - NN) * DD + 255) / 256, 256, 0, stream>>>(zbf);

    dim3 ggrid(MPAD / GBM, DD / GBM);
    for (int l = 0; l < NL; ++l) {
        k_agg_bf<<<NN, 64, 0, stream>>>(hbf, row_start, elist, zbf);
        k_mfma_gemm<1><<<ggrid, 256, 0, stream>>>(zbf, wt + (size_t)l * DD * DD, b1 + l * DD, h1bf);
        k_mfma_gemm<0><<<ggrid, 256, 0, stream>>>(h1bf, wt + (size_t)(3 + l) * DD * DD, b2 + l * DD, buf0);
        k_bnstats<<<400, 256, 0, stream>>>(buf0, sums);
        k_bnscale<<<1, 256, 0, stream>>>(sums, gamma + l * DD, beta + l * DD, ss);
        k_bnpool<<<NG, 256, 0, stream>>>(buf0, ss, gstart, hbf, out, l);
    }
}

// Round 4
// 686.092 us; speedup vs baseline: 2.4437x; 1.1484x over previous
//
#include <hip/hip_runtime.h>

#define NN 50000
#define NE 800000
#define NG 256
#define DD 256
#define NL 3
#define BN_EPS 1e-5f
#define MPAD 50048   // 391 * 128
#define CAP 96       // per-node edge bucket capacity (Poisson(16) tail @96 ~ 1e-40)

typedef short bf16x8 __attribute__((ext_vector_type(8)));
typedef float f32x4 __attribute__((ext_vector_type(4)));

__device__ __forceinline__ unsigned short f2bf(float f) {
    unsigned int u = __float_as_uint(f);
    u += 0x7FFFu + ((u >> 16) & 1u);
    return (unsigned short)(u >> 16);
}
__device__ __forceinline__ float bf2f(unsigned short s) {
    return __uint_as_float(((unsigned int)s) << 16);
}

// ---------- init: zero deg (doubles as scatter cursor) and BN sums ----------
__global__ void k_init(int* __restrict__ deg, float* __restrict__ sums) {
    int i = blockIdx.x * blockDim.x + threadIdx.x;
    if (i < NN) deg[i] = 0;
    if (i < 2 * DD) sums[i] = 0.f;
}

// one-pass CSR build: bucket scatter; deg ends up as the in-degree
__global__ void k_scatter(const int* __restrict__ ei, int* __restrict__ deg,
                          int* __restrict__ elist) {
    int e = blockIdx.x * blockDim.x + threadIdx.x;
    if (e >= NE) return;
    int s = ei[e];          // src
    int d = ei[NE + e];     // dst
    int pos = atomicAdd(&deg[d], 1);
    elist[d * CAP + pos] = s;
}

// graph boundaries via binary search over sorted batch
__global__ void k_gbounds(const int* __restrict__ batch, int* __restrict__ gstart) {
    int g = threadIdx.x;   // 0..255
    int lo = 0, hi = NN;
    while (lo < hi) {
        int mid = (lo + hi) >> 1;
        if (batch[mid] < g) lo = mid + 1; else hi = mid;
    }
    gstart[g] = lo;
    if (g == 0) gstart[NG] = NN;
}

// ---------- conversions ----------
__global__ void k_f2bf(const float* __restrict__ in, unsigned short* __restrict__ out, int n4) {
    int i = blockIdx.x * blockDim.x + threadIdx.x;
    if (i >= n4) return;
    float4 v = ((const float4*)in)[i];
    ushort4 o;
    o.x = f2bf(v.x); o.y = f2bf(v.y); o.z = f2bf(v.z); o.w = f2bf(v.w);
    ((ushort4*)out)[i] = o;
}

__global__ void k_zpad(unsigned short* p) {
    int i = blockIdx.x * blockDim.x + threadIdx.x;
    const int total = (MPAD - NN) * DD;
    if (i < total) p[NN * DD + i] = 0;
}

// wt[mat][n][k] = w[mat][k][n] as bf16; mats 0..2 = w1 layers, 3..5 = w2 layers
__global__ void k_wconv(const float* __restrict__ w1, const float* __restrict__ w2,
                        unsigned short* __restrict__ wt) {
    int flat = blockIdx.x * blockDim.x + threadIdx.x;
    if (flat >= 6 * 65536) return;
    int mat = flat >> 16;
    int n = (flat >> 8) & 255;
    int k = flat & 255;
    const float* src = (mat < 3) ? (w1 + ((size_t)mat << 16)) : (w2 + ((size_t)(mat - 3) << 16));
    wt[flat] = f2bf(src[k * 256 + n]);
}

// ---------- aggregation: z0 = h + sum_{src} h[src], bf16 in/out, fp32 accum ----------
__global__ __launch_bounds__(64) void k_agg_bf(const unsigned short* __restrict__ h,
                                               const int* __restrict__ deg,
                                               const int* __restrict__ elist,
                                               unsigned short* __restrict__ z0) {
    int node = blockIdx.x;
    int lane = threadIdx.x;
    const ushort4* h4 = (const ushort4*)h;
    ushort4 own = h4[node * 64 + lane];
    float a0 = bf2f(own.x), a1 = bf2f(own.y), a2 = bf2f(own.z), a3 = bf2f(own.w);
    int n = deg[node];
    const int* el = elist + node * CAP;
    for (int i = 0; i < n; ++i) {
        int s = el[i];
        ushort4 v = h4[s * 64 + lane];
        a0 += bf2f(v.x); a1 += bf2f(v.y); a2 += bf2f(v.z); a3 += bf2f(v.w);
    }
    ushort4 o;
    o.x = f2bf(a0); o.y = f2bf(a1); o.z = f2bf(a2); o.w = f2bf(a3);
    ((ushort4*)z0)[node * 64 + lane] = o;
}

// ---------- bf16 MFMA GEMM: C = relu(A @ W + bias) ----------
#define GBM 128
#define GBK 64
template<int OUT_BF16>
__global__ __launch_bounds__(256) void k_mfma_gemm(const unsigned short* __restrict__ A,
                                                   const unsigned short* __restrict__ BT,
                                                   const float* __restrict__ bias,
                                                   void* __restrict__ Cout) {
    __shared__ short As[GBM * GBK];
    __shared__ short Bs[GBM * GBK];
    int tid = threadIdx.x;
    int lane = tid & 63;
    int wave = tid >> 6;
    int wr = wave >> 1, wc = wave & 1;
    long m0 = (long)blockIdx.x * GBM;
    int n0 = blockIdx.y * GBM;
    const int r = lane & 15, hi = lane >> 4;

    f32x4 acc[4][4];
    #pragma unroll
    for (int m = 0; m < 4; ++m)
        #pragma unroll
        for (int n = 0; n < 4; ++n)
            acc[m][n] = (f32x4){0.f, 0.f, 0.f, 0.f};

    for (int k0 = 0; k0 < DD; k0 += GBK) {
        #pragma unroll
        for (int p = 0; p < 4; ++p) {
            int flat = p * 256 + tid;
            int row = flat >> 3;
            int c8 = flat & 7;
            int slot = c8 ^ (row & 7);
            bf16x8 va = *(const bf16x8*)(A + (m0 + row) * DD + k0 + c8 * 8);
            *(bf16x8*)(As + row * GBK + slot * 8) = va;
            bf16x8 vb = *(const bf16x8*)(BT + (long)(n0 + row) * DD + k0 + c8 * 8);
            *(bf16x8*)(Bs + row * GBK + slot * 8) = vb;
        }
        __syncthreads();

        bf16x8 af[4][2], bfr[4][2];
        #pragma unroll
        for (int m = 0; m < 4; ++m) {
            int row = wr * 64 + m * 16 + r;
            #pragma unroll
            for (int kk = 0; kk < 2; ++kk) {
                int slot = (kk * 4 + hi) ^ (row & 7);
                af[m][kk] = *(const bf16x8*)(As + row * GBK + slot * 8);
            }
        }
        #pragma unroll
        for (int n = 0; n < 4; ++n) {
            int col = wc * 64 + n * 16 + r;
            #pragma unroll
            for (int kk = 0; kk < 2; ++kk) {
                int slot = (kk * 4 + hi) ^ (col & 7);
                bfr[n][kk] = *(const bf16x8*)(Bs + col * GBK + slot * 8);
            }
        }
        #pragma unroll
        for (int kk = 0; kk < 2; ++kk)
            #pragma unroll
            for (int m = 0; m < 4; ++m)
                #pragma unroll
                for (int n = 0; n < 4; ++n)
                    acc[m][n] = __builtin_amdgcn_mfma_f32_16x16x32_bf16(af[m][kk], bfr[n][kk], acc[m][n], 0, 0, 0);
        __syncthreads();
    }

    #pragma unroll
    for (int n = 0; n < 4; ++n) {
        int col = n0 + wc * 64 + n * 16 + r;
        float bv = bias[col];
        #pragma unroll
        for (int m = 0; m < 4; ++m) {
            #pragma unroll
            for (int j = 0; j < 4; ++j) {
                long grow = m0 + wr * 64 + m * 16 + hi * 4 + j;
                float v = acc[m][n][j] + bv;
                v = v > 0.f ? v : 0.f;
                if (OUT_BF16) ((unsigned short*)Cout)[grow * DD + col] = f2bf(v);
                else          ((float*)Cout)[grow * DD + col] = v;
            }
        }
    }
}

// ---------- BN ----------
__global__ __launch_bounds__(256) void k_bnstats(const float* __restrict__ z,
                                                 float* __restrict__ sums) {
    int col = threadIdx.x;
    float s = 0.f, s2 = 0.f;
    for (int r = blockIdx.x; r < NN; r += gridDim.x) {
        float v = z[r * DD + col];
        s += v; s2 += v * v;
    }
    atomicAdd(&sums[col], s);
    atomicAdd(&sums[DD + col], s2);
}

// compute scale/shift, then re-zero sums for the next layer's bnstats
__global__ void k_bnscale(float* __restrict__ sums, const float* __restrict__ gamma,
                          const float* __restrict__ beta, float* __restrict__ ss) {
    int c = threadIdx.x;
    float mean = sums[c] * (1.0f / NN);
    float var = sums[DD + c] * (1.0f / NN) - mean * mean;
    float sc = gamma[c] * rsqrtf(var + BN_EPS);
    ss[c] = sc;
    ss[DD + c] = beta[c] - mean * sc;
    sums[c] = 0.f;
    sums[DD + c] = 0.f;
}

// fused BN-apply + bf16 emit + global_add_pool (one block per graph)
__global__ __launch_bounds__(256) void k_bnpool(const float* __restrict__ z,
                                                const float* __restrict__ ss,
                                                const int* __restrict__ gstart,
                                                unsigned short* __restrict__ hbf,
                                                float* __restrict__ out, int layer) {
    int g = blockIdx.x, c = threadIdx.x;
    float sc = ss[c];
    float sh = ss[DD + c];
    int lo = gstart[g], hi = gstart[g + 1];
    float s = 0.f;
    for (int r = lo; r < hi; ++r) {
        float v = z[r * DD + c] * sc + sh;
        s += v;
        hbf[r * DD + c] = f2bf(v);
    }
    out[g * (NL * DD) + layer * DD + c] = s;
}

extern "C" void kernel_launch(void* const* d_in, const int* in_sizes, int n_in,
                              void* d_out, int out_size, void* d_ws, size_t ws_size,
                              hipStream_t stream) {
    const float* x     = (const float*)d_in[0];
    const int*   ei    = (const int*)d_in[1];
    const int*   batch = (const int*)d_in[2];
    const float* w1    = (const float*)d_in[3];
    const float* b1    = (const float*)d_in[4];
    const float* w2    = (const float*)d_in[5];
    const float* b2    = (const float*)d_in[6];
    const float* gamma = (const float*)d_in[7];
    const float* beta  = (const float*)d_in[8];
    float* out = (float*)d_out;

    char* ws = (char*)d_ws;
    size_t off = 0;
    auto alloc = [&](size_t bytes) -> void* {
        void* p = ws + off;
        off += (bytes + 255) & ~size_t(255);
        return p;
    };
    float*          buf0 = (float*)alloc((size_t)MPAD * DD * 4);          // fp32 GEMM2 out
    unsigned short* zbf  = (unsigned short*)alloc((size_t)MPAD * DD * 2); // agg out (GEMM1 A)
    unsigned short* h1bf = (unsigned short*)alloc((size_t)MPAD * DD * 2); // GEMM1 out (GEMM2 A)
    unsigned short* hbf  = (unsigned short*)alloc((size_t)NN * DD * 2);   // h as bf16
    unsigned short* wt   = (unsigned short*)alloc((size_t)6 * DD * DD * 2);
    int* deg    = (int*)alloc((size_t)NN * 4);
    int* elist  = (int*)alloc((size_t)NN * CAP * 4);
    int* gstart = (int*)alloc((size_t)(NG + 1) * 4);
    float* sums = (float*)alloc(2 * DD * 4);
    float* ss   = (float*)alloc(2 * DD * 4);

    // CSR (one atomic pass) + graph boundaries (binary search)
    k_init<<<(NN + 255) / 256, 256, 0, stream>>>(deg, sums);
    k_scatter<<<(NE + 255) / 256, 256, 0, stream>>>(ei, deg, elist);
    k_gbounds<<<1, 256, 0, stream>>>(batch, gstart);

    // weight transpose+convert, x -> bf16, zero pad rows of zbf
    k_wconv<<<(6 * 65536 + 255) / 256, 256, 0, stream>>>(w1, w2, wt);
    k_f2bf<<<(NN * DD / 4 + 255) / 256, 256, 0, stream>>>(x, hbf, NN * DD / 4);
    k_zpad<<<((MPAD - NN) * DD + 255) / 256, 256, 0, stream>>>(zbf);

    dim3 ggrid(MPAD / GBM, DD / GBM);
    for (int l = 0; l < NL; ++l) {
        k_agg_bf<<<NN, 64, 0, stream>>>(hbf, deg, elist, zbf);
        k_mfma_gemm<1><<<ggrid, 256, 0, stream>>>(zbf, wt + (size_t)l * DD * DD, b1 + l * DD, h1bf);
        k_mfma_gemm<0><<<ggrid, 256, 0, stream>>>(h1bf, wt + (size_t)(3 + l) * DD * DD, b2 + l * DD, buf0);
        k_bnstats<<<400, 256, 0, stream>>>(buf0, sums);
        k_bnscale<<<1, 256, 0, stream>>>(sums, gamma + l * DD, beta + l * DD, ss);
        k_bnpool<<<NG, 256, 0, stream>>>(buf0, ss, gstart, hbf, out, l);
    }
}

// Round 5
// 463.169 us; speedup vs baseline: 3.6199x; 1.4813x over previous
//
#include <hip/hip_runtime.h>

#define NN 50000
#define NE 800000
#define NG 256
#define DD 256
#define NL 3
#define BN_EPS 1e-5f
#define MPAD 50048   // 391 * 128
#define CAP 96       // per-node edge bucket capacity (Poisson(16) tail @96 ~ 1e-40)
#define NMB 391      // MPAD / 128 (GEMM m-blocks)

typedef short bf16x8 __attribute__((ext_vector_type(8)));
typedef float f32x4 __attribute__((ext_vector_type(4)));

__device__ __forceinline__ unsigned short f2bf(float f) {
    unsigned int u = __float_as_uint(f);
    u += 0x7FFFu + ((u >> 16) & 1u);
    return (unsigned short)(u >> 16);
}
__device__ __forceinline__ float bf2f(unsigned short s) {
    return __uint_as_float(((unsigned int)s) << 16);
}

// ---------- init: zero deg (doubles as scatter cursor) ----------
__global__ void k_init(int* __restrict__ deg) {
    int i = blockIdx.x * blockDim.x + threadIdx.x;
    if (i < NN) deg[i] = 0;
}

// one-pass CSR build: bucket scatter; deg ends up as the in-degree
__global__ void k_scatter(const int* __restrict__ ei, int* __restrict__ deg,
                          int* __restrict__ elist) {
    int e = blockIdx.x * blockDim.x + threadIdx.x;
    if (e >= NE) return;
    int s = ei[e];          // src
    int d = ei[NE + e];     // dst
    int pos = atomicAdd(&deg[d], 1);
    elist[d * CAP + pos] = s;
}

// graph boundaries via binary search over sorted batch
__global__ void k_gbounds(const int* __restrict__ batch, int* __restrict__ gstart) {
    int g = threadIdx.x;   // 0..255
    int lo = 0, hi = NN;
    while (lo < hi) {
        int mid = (lo + hi) >> 1;
        if (batch[mid] < g) lo = mid + 1; else hi = mid;
    }
    gstart[g] = lo;
    if (g == 0) gstart[NG] = NN;
}

// ---------- conversions ----------
__global__ void k_f2bf(const float* __restrict__ in, unsigned short* __restrict__ out, int n4) {
    int i = blockIdx.x * blockDim.x + threadIdx.x;
    if (i >= n4) return;
    float4 v = ((const float4*)in)[i];
    ushort4 o;
    o.x = f2bf(v.x); o.y = f2bf(v.y); o.z = f2bf(v.z); o.w = f2bf(v.w);
    ((ushort4*)out)[i] = o;
}

__global__ void k_zpad(unsigned short* p) {
    int i = blockIdx.x * blockDim.x + threadIdx.x;
    const int total = (MPAD - NN) * DD;
    if (i < total) p[NN * DD + i] = 0;
}

// wt[mat][n][k] = w[mat][k][n] as bf16; mats 0..2 = w1 layers, 3..5 = w2 layers
__global__ void k_wconv(const float* __restrict__ w1, const float* __restrict__ w2,
                        unsigned short* __restrict__ wt) {
    int flat = blockIdx.x * blockDim.x + threadIdx.x;
    if (flat >= 6 * 65536) return;
    int mat = flat >> 16;
    int n = (flat >> 8) & 255;
    int k = flat & 255;
    const float* src = (mat < 3) ? (w1 + ((size_t)mat << 16)) : (w2 + ((size_t)(mat - 3) << 16));
    wt[flat] = f2bf(src[k * 256 + n]);
}

// ---------- aggregation: z0 = h + sum_{src} h[src], bf16 in/out, fp32 accum ----------
__global__ __launch_bounds__(64) void k_agg_bf(const unsigned short* __restrict__ h,
                                               const int* __restrict__ deg,
                                               const int* __restrict__ elist,
                                               unsigned short* __restrict__ z0) {
    int node = blockIdx.x;
    int lane = threadIdx.x;
    const ushort4* h4 = (const ushort4*)h;
    ushort4 own = h4[node * 64 + lane];
    float a0 = bf2f(own.x), a1 = bf2f(own.y), a2 = bf2f(own.z), a3 = bf2f(own.w);
    int n = deg[node];
    const int* el = elist + node * CAP;
    for (int i = 0; i < n; ++i) {
        int s = el[i];
        ushort4 v = h4[s * 64 + lane];
        a0 += bf2f(v.x); a1 += bf2f(v.y); a2 += bf2f(v.z); a3 += bf2f(v.w);
    }
    ushort4 o;
    o.x = f2bf(a0); o.y = f2bf(a1); o.z = f2bf(a2); o.w = f2bf(a3);
    ((ushort4*)z0)[node * 64 + lane] = o;
}

// ---------- bf16 MFMA GEMM: C = relu(A @ W + bias), optional fused BN partial stats ----------
#define GBM 128
#define GBK 64
template<int OUT_BF16, int STATS>
__global__ __launch_bounds__(256) void k_mfma_gemm(const unsigned short* __restrict__ A,
                                                   const unsigned short* __restrict__ BT,
                                                   const float* __restrict__ bias,
                                                   void* __restrict__ Cout,
                                                   float* __restrict__ pstat) {
    __shared__ short As[GBM * GBK];
    __shared__ short Bs[GBM * GBK];
    __shared__ float spart[2][128][2];   // [wr][col_local][sum|sumsq]
    int tid = threadIdx.x;
    int lane = tid & 63;
    int wave = tid >> 6;
    int wr = wave >> 1, wc = wave & 1;
    long m0 = (long)blockIdx.x * GBM;
    int n0 = blockIdx.y * GBM;
    const int r = lane & 15, hi = lane >> 4;

    f32x4 acc[4][4];
    #pragma unroll
    for (int m = 0; m < 4; ++m)
        #pragma unroll
        for (int n = 0; n < 4; ++n)
            acc[m][n] = (f32x4){0.f, 0.f, 0.f, 0.f};

    for (int k0 = 0; k0 < DD; k0 += GBK) {
        #pragma unroll
        for (int p = 0; p < 4; ++p) {
            int flat = p * 256 + tid;
            int row = flat >> 3;
            int c8 = flat & 7;
            int slot = c8 ^ (row & 7);
            bf16x8 va = *(const bf16x8*)(A + (m0 + row) * DD + k0 + c8 * 8);
            *(bf16x8*)(As + row * GBK + slot * 8) = va;
            bf16x8 vb = *(const bf16x8*)(BT + (long)(n0 + row) * DD + k0 + c8 * 8);
            *(bf16x8*)(Bs + row * GBK + slot * 8) = vb;
        }
        __syncthreads();

        bf16x8 af[4][2], bfr[4][2];
        #pragma unroll
        for (int m = 0; m < 4; ++m) {
            int row = wr * 64 + m * 16 + r;
            #pragma unroll
            for (int kk = 0; kk < 2; ++kk) {
                int slot = (kk * 4 + hi) ^ (row & 7);
                af[m][kk] = *(const bf16x8*)(As + row * GBK + slot * 8);
            }
        }
        #pragma unroll
        for (int n = 0; n < 4; ++n) {
            int col = wc * 64 + n * 16 + r;
            #pragma unroll
            for (int kk = 0; kk < 2; ++kk) {
                int slot = (kk * 4 + hi) ^ (col & 7);
                bfr[n][kk] = *(const bf16x8*)(Bs + col * GBK + slot * 8);
            }
        }
        #pragma unroll
        for (int kk = 0; kk < 2; ++kk)
            #pragma unroll
            for (int m = 0; m < 4; ++m)
                #pragma unroll
                for (int n = 0; n < 4; ++n)
                    acc[m][n] = __builtin_amdgcn_mfma_f32_16x16x32_bf16(af[m][kk], bfr[n][kk], acc[m][n], 0, 0, 0);
        __syncthreads();
    }

    // epilogue: bias + relu (+ per-block BN column partials)
    #pragma unroll
    for (int n = 0; n < 4; ++n) {
        int col = n0 + wc * 64 + n * 16 + r;
        float bv = bias[col];
        float cs = 0.f, cs2 = 0.f;
        #pragma unroll
        for (int m = 0; m < 4; ++m) {
            #pragma unroll
            for (int j = 0; j < 4; ++j) {
                long grow = m0 + wr * 64 + m * 16 + hi * 4 + j;
                float v = acc[m][n][j] + bv;
                v = v > 0.f ? v : 0.f;
                if (OUT_BF16) ((unsigned short*)Cout)[grow * DD + col] = f2bf(v);
                else          ((float*)Cout)[grow * DD + col] = v;
                if (STATS) {
                    float vm = (grow < NN) ? v : 0.f;
                    cs += vm; cs2 += vm * vm;
                }
            }
        }
        if (STATS) {
            // reduce across hi groups (rows) within the wave
            cs  += __shfl_xor(cs, 16);  cs  += __shfl_xor(cs, 32);
            cs2 += __shfl_xor(cs2, 16); cs2 += __shfl_xor(cs2, 32);
            if (hi == 0) {
                spart[wr][wc * 64 + n * 16 + r][0] = cs;
                spart[wr][wc * 64 + n * 16 + r][1] = cs2;
            }
        }
    }
    if (STATS) {
        __syncthreads();
        if (tid < 128) {
            float s  = spart[0][tid][0] + spart[1][tid][0];
            float s2 = spart[0][tid][1] + spart[1][tid][1];
            pstat[(size_t)blockIdx.x * 512 + n0 + tid] = s;
            pstat[(size_t)blockIdx.x * 512 + 256 + n0 + tid] = s2;
        }
    }
}

// reduce per-block partials -> BN scale/shift (one block per column, fixed tree)
__global__ __launch_bounds__(256) void k_bnscale2(const float* __restrict__ pstat,
                                                  const float* __restrict__ gamma,
                                                  const float* __restrict__ beta,
                                                  float* __restrict__ ss) {
    int c = blockIdx.x;
    int t = threadIdx.x;
    float s = 0.f, s2 = 0.f;
    for (int mb = t; mb < NMB; mb += 256) {
        s  += pstat[(size_t)mb * 512 + c];
        s2 += pstat[(size_t)mb * 512 + 256 + c];
    }
    __shared__ float rs[256], rs2[256];
    rs[t] = s; rs2[t] = s2;
    __syncthreads();
    #pragma unroll
    for (int d = 128; d > 0; d >>= 1) {
        if (t < d) { rs[t] += rs[t + d]; rs2[t] += rs2[t + d]; }
        __syncthreads();
    }
    if (t == 0) {
        float mean = rs[0] * (1.0f / NN);
        float var = rs2[0] * (1.0f / NN) - mean * mean;
        float sc = gamma[c] * rsqrtf(var + BN_EPS);
        ss[c] = sc;
        ss[DD + c] = beta[c] - mean * sc;
    }
}

// fused BN-apply + bf16 emit + global_add_pool; 512 thr: quad q (64) x rowgroup rg (8)
__global__ __launch_bounds__(512) void k_bnpool(const float* __restrict__ z,
                                                const float* __restrict__ ss,
                                                const int* __restrict__ gstart,
                                                unsigned short* __restrict__ hbf,
                                                float* __restrict__ out, int layer) {
    __shared__ float4 red[8][64];
    int g = blockIdx.x;
    int t = threadIdx.x;
    int q = t & 63, rg = t >> 6;
    float4 sc = ((const float4*)ss)[q];
    float4 sh = ((const float4*)(ss + DD))[q];
    int lo = gstart[g], hi = gstart[g + 1];
    float4 s = {0.f, 0.f, 0.f, 0.f};
    const float4* z4 = (const float4*)z;
    ushort4* h4 = (ushort4*)hbf;
    for (int r = lo + rg; r < hi; r += 8) {
        float4 v = z4[r * 64 + q];
        v.x = v.x * sc.x + sh.x;
        v.y = v.y * sc.y + sh.y;
        v.z = v.z * sc.z + sh.z;
        v.w = v.w * sc.w + sh.w;
        s.x += v.x; s.y += v.y; s.z += v.z; s.w += v.w;
        ushort4 o;
        o.x = f2bf(v.x); o.y = f2bf(v.y); o.z = f2bf(v.z); o.w = f2bf(v.w);
        h4[r * 64 + q] = o;
    }
    red[rg][q] = s;
    __syncthreads();
    if (rg < 4) {
        float4 a = red[rg][q], b = red[rg + 4][q];
        a.x += b.x; a.y += b.y; a.z += b.z; a.w += b.w;
        red[rg][q] = a;
    }
    __syncthreads();
    if (rg < 2) {
        float4 a = red[rg][q], b = red[rg + 2][q];
        a.x += b.x; a.y += b.y; a.z += b.z; a.w += b.w;
        red[rg][q] = a;
    }
    __syncthreads();
    if (rg == 0) {
        float4 a = red[0][q], b = red[1][q];
        a.x += b.x; a.y += b.y; a.z += b.z; a.w += b.w;
        ((float4*)(out + (size_t)g * (NL * DD) + layer * DD))[q] = a;
    }
}

extern "C" void kernel_launch(void* const* d_in, const int* in_sizes, int n_in,
                              void* d_out, int out_size, void* d_ws, size_t ws_size,
                              hipStream_t stream) {
    const float* x     = (const float*)d_in[0];
    const int*   ei    = (const int*)d_in[1];
    const int*   batch = (const int*)d_in[2];
    const float* w1    = (const float*)d_in[3];
    const float* b1    = (const float*)d_in[4];
    const float* w2    = (const float*)d_in[5];
    const float* b2    = (const float*)d_in[6];
    const float* gamma = (const float*)d_in[7];
    const float* beta  = (const float*)d_in[8];
    float* out = (float*)d_out;

    char* ws = (char*)d_ws;
    size_t off = 0;
    auto alloc = [&](size_t bytes) -> void* {
        void* p = ws + off;
        off += (bytes + 255) & ~size_t(255);
        return p;
    };
    float*          buf0 = (float*)alloc((size_t)MPAD * DD * 4);          // fp32 GEMM2 out
    unsigned short* zbf  = (unsigned short*)alloc((size_t)MPAD * DD * 2); // agg out (GEMM1 A)
    unsigned short* h1bf = (unsigned short*)alloc((size_t)MPAD * DD * 2); // GEMM1 out (GEMM2 A)
    unsigned short* hbf  = (unsigned short*)alloc((size_t)NN * DD * 2);   // h as bf16
    unsigned short* wt   = (unsigned short*)alloc((size_t)6 * DD * DD * 2);
    int* deg    = (int*)alloc((size_t)NN * 4);
    int* elist  = (int*)alloc((size_t)NN * CAP * 4);
    int* gstart = (int*)alloc((size_t)(NG + 1) * 4);
    float* pstat = (float*)alloc((size_t)NMB * 512 * 4);
    float* ss   = (float*)alloc(2 * DD * 4);

    // CSR (one atomic pass) + graph boundaries (binary search)
    k_init<<<(NN + 255) / 256, 256, 0, stream>>>(deg);
    k_scatter<<<(NE + 255) / 256, 256, 0, stream>>>(ei, deg, elist);
    k_gbounds<<<1, 256, 0, stream>>>(batch, gstart);

    // weight transpose+convert, x -> bf16, zero pad rows of zbf
    k_wconv<<<(6 * 65536 + 255) / 256, 256, 0, stream>>>(w1, w2, wt);
    k_f2bf<<<(NN * DD / 4 + 255) / 256, 256, 0, stream>>>(x, hbf, NN * DD / 4);
    k_zpad<<<((MPAD - NN) * DD + 255) / 256, 256, 0, stream>>>(zbf);

    dim3 ggrid(MPAD / GBM, DD / GBM);
    for (int l = 0; l < NL; ++l) {
        k_agg_bf<<<NN, 64, 0, stream>>>(hbf, deg, elist, zbf);
        k_mfma_gemm<1, 0><<<ggrid, 256, 0, stream>>>(zbf, wt + (size_t)l * DD * DD, b1 + l * DD, h1bf, nullptr);
        k_mfma_gemm<0, 1><<<ggrid, 256, 0, stream>>>(h1bf, wt + (size_t)(3 + l) * DD * DD, b2 + l * DD, buf0, pstat);
        k_bnscale2<<<DD, 256, 0, stream>>>(pstat, gamma + l * DD, beta + l * DD, ss);
        k_bnpool<<<NG, 512, 0, stream>>>(buf0, ss, gstart, hbf, out, l);
    }
}

// Round 6
// 451.892 us; speedup vs baseline: 3.7102x; 1.0250x over previous
//
#include <hip/hip_runtime.h>

#define NN 50000
#define NE 800000
#define NG 256
#define DD 256
#define NL 3
#define BN_EPS 1e-5f
#define MPAD 50048   // 391 * 128
#define CAP 96       // per-node edge bucket capacity (Poisson(16) tail @96 ~ 1e-40)
#define NMB 391      // MPAD / 128 (GEMM m-blocks)

typedef short bf16x8 __attribute__((ext_vector_type(8)));
typedef float f32x4 __attribute__((ext_vector_type(4)));

__device__ __forceinline__ unsigned short f2bf(float f) {
    unsigned int u = __float_as_uint(f);
    u += 0x7FFFu + ((u >> 16) & 1u);
    return (unsigned short)(u >> 16);
}
__device__ __forceinline__ float bf2f(unsigned short s) {
    return __uint_as_float(((unsigned int)s) << 16);
}

// ---------- init: zero deg (doubles as scatter cursor) ----------
__global__ void k_init(int* __restrict__ deg) {
    int i = blockIdx.x * blockDim.x + threadIdx.x;
    if (i < NN) deg[i] = 0;
}

// one-pass CSR build: bucket scatter (u16 src); deg ends up as the in-degree
__global__ void k_scatter(const int* __restrict__ ei, int* __restrict__ deg,
                          unsigned short* __restrict__ elist) {
    int e = blockIdx.x * blockDim.x + threadIdx.x;
    if (e >= NE) return;
    int s = ei[e];          // src  (< 65536)
    int d = ei[NE + e];     // dst
    int pos = atomicAdd(&deg[d], 1);
    elist[(size_t)d * CAP + pos] = (unsigned short)s;
}

// graph boundaries via binary search over sorted batch
__global__ void k_gbounds(const int* __restrict__ batch, int* __restrict__ gstart) {
    int g = threadIdx.x;   // 0..255
    int lo = 0, hi = NN;
    while (lo < hi) {
        int mid = (lo + hi) >> 1;
        if (batch[mid] < g) lo = mid + 1; else hi = mid;
    }
    gstart[g] = lo;
    if (g == 0) gstart[NG] = NN;
}

// ---------- conversions ----------
__global__ void k_f2bf(const float* __restrict__ in, unsigned short* __restrict__ out, int n4) {
    int i = blockIdx.x * blockDim.x + threadIdx.x;
    if (i >= n4) return;
    float4 v = ((const float4*)in)[i];
    ushort4 o;
    o.x = f2bf(v.x); o.y = f2bf(v.y); o.z = f2bf(v.z); o.w = f2bf(v.w);
    ((ushort4*)out)[i] = o;
}

__global__ void k_zpad(unsigned short* p) {
    int i = blockIdx.x * blockDim.x + threadIdx.x;
    const int total = (MPAD - NN) * DD;
    if (i < total) p[NN * DD + i] = 0;
}

// wt[mat][n][k] = w[mat][k][n] as bf16; mats 0..2 = w1 layers, 3..5 = w2 layers
__global__ void k_wconv(const float* __restrict__ w1, const float* __restrict__ w2,
                        unsigned short* __restrict__ wt) {
    int flat = blockIdx.x * blockDim.x + threadIdx.x;
    if (flat >= 6 * 65536) return;
    int mat = flat >> 16;
    int n = (flat >> 8) & 255;
    int k = flat & 255;
    const float* src = (mat < 3) ? (w1 + ((size_t)mat << 16)) : (w2 + ((size_t)(mat - 3) << 16));
    wt[flat] = f2bf(src[k * 256 + n]);
}

// ---------- aggregation: z0 = h + sum_{src} h[src], bf16 in/out, fp32 accum ----------
// unroll-8 gather: 8 independent row-loads in flight per iteration (latency -> MLP),
// accumulation strictly in elist order (bitwise identical to scalar loop).
__global__ __launch_bounds__(64) void k_agg_bf(const unsigned short* __restrict__ h,
                                               const int* __restrict__ deg,
                                               const unsigned short* __restrict__ elist,
                                               unsigned short* __restrict__ z0) {
    int node = blockIdx.x;
    int lane = threadIdx.x;
    const ushort4* h4 = (const ushort4*)h;
    ushort4 own = h4[(size_t)node * 64 + lane];
    float a0 = bf2f(own.x), a1 = bf2f(own.y), a2 = bf2f(own.z), a3 = bf2f(own.w);
    int n = deg[node];
    const unsigned short* el = elist + (size_t)node * CAP;
    int i = 0;
    for (; i + 8 <= n; i += 8) {
        int s0 = el[i + 0], s1 = el[i + 1], s2 = el[i + 2], s3 = el[i + 3];
        int s4 = el[i + 4], s5 = el[i + 5], s6 = el[i + 6], s7 = el[i + 7];
        ushort4 v0 = h4[(size_t)s0 * 64 + lane];
        ushort4 v1 = h4[(size_t)s1 * 64 + lane];
        ushort4 v2 = h4[(size_t)s2 * 64 + lane];
        ushort4 v3 = h4[(size_t)s3 * 64 + lane];
        ushort4 v4 = h4[(size_t)s4 * 64 + lane];
        ushort4 v5 = h4[(size_t)s5 * 64 + lane];
        ushort4 v6 = h4[(size_t)s6 * 64 + lane];
        ushort4 v7 = h4[(size_t)s7 * 64 + lane];
        a0 += bf2f(v0.x); a1 += bf2f(v0.y); a2 += bf2f(v0.z); a3 += bf2f(v0.w);
        a0 += bf2f(v1.x); a1 += bf2f(v1.y); a2 += bf2f(v1.z); a3 += bf2f(v1.w);
        a0 += bf2f(v2.x); a1 += bf2f(v2.y); a2 += bf2f(v2.z); a3 += bf2f(v2.w);
        a0 += bf2f(v3.x); a1 += bf2f(v3.y); a2 += bf2f(v3.z); a3 += bf2f(v3.w);
        a0 += bf2f(v4.x); a1 += bf2f(v4.y); a2 += bf2f(v4.z); a3 += bf2f(v4.w);
        a0 += bf2f(v5.x); a1 += bf2f(v5.y); a2 += bf2f(v5.z); a3 += bf2f(v5.w);
        a0 += bf2f(v6.x); a1 += bf2f(v6.y); a2 += bf2f(v6.z); a3 += bf2f(v6.w);
        a0 += bf2f(v7.x); a1 += bf2f(v7.y); a2 += bf2f(v7.z); a3 += bf2f(v7.w);
    }
    for (; i < n; ++i) {
        int s = el[i];
        ushort4 v = h4[(size_t)s * 64 + lane];
        a0 += bf2f(v.x); a1 += bf2f(v.y); a2 += bf2f(v.z); a3 += bf2f(v.w);
    }
    ushort4 o;
    o.x = f2bf(a0); o.y = f2bf(a1); o.z = f2bf(a2); o.w = f2bf(a3);
    ((ushort4*)z0)[(size_t)node * 64 + lane] = o;
}

// ---------- bf16 MFMA GEMM: C = relu(A @ W + bias), optional fused BN partial stats ----------
#define GBM 128
#define GBK 64
template<int OUT_BF16, int STATS>
__global__ __launch_bounds__(256) void k_mfma_gemm(const unsigned short* __restrict__ A,
                                                   const unsigned short* __restrict__ BT,
                                                   const float* __restrict__ bias,
                                                   void* __restrict__ Cout,
                                                   float* __restrict__ pstat) {
    __shared__ short As[GBM * GBK];
    __shared__ short Bs[GBM * GBK];
    __shared__ float spart[2][128][2];   // [wr][col_local][sum|sumsq]
    int tid = threadIdx.x;
    int lane = tid & 63;
    int wave = tid >> 6;
    int wr = wave >> 1, wc = wave & 1;
    long m0 = (long)blockIdx.x * GBM;
    int n0 = blockIdx.y * GBM;
    const int r = lane & 15, hi = lane >> 4;

    f32x4 acc[4][4];
    #pragma unroll
    for (int m = 0; m < 4; ++m)
        #pragma unroll
        for (int n = 0; n < 4; ++n)
            acc[m][n] = (f32x4){0.f, 0.f, 0.f, 0.f};

    for (int k0 = 0; k0 < DD; k0 += GBK) {
        #pragma unroll
        for (int p = 0; p < 4; ++p) {
            int flat = p * 256 + tid;
            int row = flat >> 3;
            int c8 = flat & 7;
            int slot = c8 ^ (row & 7);
            bf16x8 va = *(const bf16x8*)(A + (m0 + row) * DD + k0 + c8 * 8);
            *(bf16x8*)(As + row * GBK + slot * 8) = va;
            bf16x8 vb = *(const bf16x8*)(BT + (long)(n0 + row) * DD + k0 + c8 * 8);
            *(bf16x8*)(Bs + row * GBK + slot * 8) = vb;
        }
        __syncthreads();

        bf16x8 af[4][2], bfr[4][2];
        #pragma unroll
        for (int m = 0; m < 4; ++m) {
            int row = wr * 64 + m * 16 + r;
            #pragma unroll
            for (int kk = 0; kk < 2; ++kk) {
                int slot = (kk * 4 + hi) ^ (row & 7);
                af[m][kk] = *(const bf16x8*)(As + row * GBK + slot * 8);
            }
        }
        #pragma unroll
        for (int n = 0; n < 4; ++n) {
            int col = wc * 64 + n * 16 + r;
            #pragma unroll
            for (int kk = 0; kk < 2; ++kk) {
                int slot = (kk * 4 + hi) ^ (col & 7);
                bfr[n][kk] = *(const bf16x8*)(Bs + col * GBK + slot * 8);
            }
        }
        #pragma unroll
        for (int kk = 0; kk < 2; ++kk)
            #pragma unroll
            for (int m = 0; m < 4; ++m)
                #pragma unroll
                for (int n = 0; n < 4; ++n)
                    acc[m][n] = __builtin_amdgcn_mfma_f32_16x16x32_bf16(af[m][kk], bfr[n][kk], acc[m][n], 0, 0, 0);
        __syncthreads();
    }

    // epilogue: bias + relu (+ per-block BN column partials)
    #pragma unroll
    for (int n = 0; n < 4; ++n) {
        int col = n0 + wc * 64 + n * 16 + r;
        float bv = bias[col];
        float cs = 0.f, cs2 = 0.f;
        #pragma unroll
        for (int m = 0; m < 4; ++m) {
            #pragma unroll
            for (int j = 0; j < 4; ++j) {
                long grow = m0 + wr * 64 + m * 16 + hi * 4 + j;
                float v = acc[m][n][j] + bv;
                v = v > 0.f ? v : 0.f;
                if (OUT_BF16) ((unsigned short*)Cout)[grow * DD + col] = f2bf(v);
                else          ((float*)Cout)[grow * DD + col] = v;
                if (STATS) {
                    float vm = (grow < NN) ? v : 0.f;
                    cs += vm; cs2 += vm * vm;
                }
            }
        }
        if (STATS) {
            cs  += __shfl_xor(cs, 16);  cs  += __shfl_xor(cs, 32);
            cs2 += __shfl_xor(cs2, 16); cs2 += __shfl_xor(cs2, 32);
            if (hi == 0) {
                spart[wr][wc * 64 + n * 16 + r][0] = cs;
                spart[wr][wc * 64 + n * 16 + r][1] = cs2;
            }
        }
    }
    if (STATS) {
        __syncthreads();
        if (tid < 128) {
            float s  = spart[0][tid][0] + spart[1][tid][0];
            float s2 = spart[0][tid][1] + spart[1][tid][1];
            pstat[(size_t)blockIdx.x * 512 + n0 + tid] = s;
            pstat[(size_t)blockIdx.x * 512 + 256 + n0 + tid] = s2;
        }
    }
}

// reduce per-block partials -> BN scale/shift (one block per column, fixed tree)
__global__ __launch_bounds__(256) void k_bnscale2(const float* __restrict__ pstat,
                                                  const float* __restrict__ gamma,
                                                  const float* __restrict__ beta,
                                                  float* __restrict__ ss) {
    int c = blockIdx.x;
    int t = threadIdx.x;
    float s = 0.f, s2 = 0.f;
    for (int mb = t; mb < NMB; mb += 256) {
        s  += pstat[(size_t)mb * 512 + c];
        s2 += pstat[(size_t)mb * 512 + 256 + c];
    }
    __shared__ float rs[256], rs2[256];
    rs[t] = s; rs2[t] = s2;
    __syncthreads();
    #pragma unroll
    for (int d = 128; d > 0; d >>= 1) {
        if (t < d) { rs[t] += rs[t + d]; rs2[t] += rs2[t + d]; }
        __syncthreads();
    }
    if (t == 0) {
        float mean = rs[0] * (1.0f / NN);
        float var = rs2[0] * (1.0f / NN) - mean * mean;
        float sc = gamma[c] * rsqrtf(var + BN_EPS);
        ss[c] = sc;
        ss[DD + c] = beta[c] - mean * sc;
    }
}

// fused BN-apply + bf16 emit + global_add_pool; 512 thr: quad q (64) x rowgroup rg (8)
__global__ __launch_bounds__(512) void k_bnpool(const float* __restrict__ z,
                                                const float* __restrict__ ss,
                                                const int* __restrict__ gstart,
                                                unsigned short* __restrict__ hbf,
                                                float* __restrict__ out, int layer) {
    __shared__ float4 red[8][64];
    int g = blockIdx.x;
    int t = threadIdx.x;
    int q = t & 63, rg = t >> 6;
    float4 sc = ((const float4*)ss)[q];
    float4 sh = ((const float4*)(ss + DD))[q];
    int lo = gstart[g], hi = gstart[g + 1];
    float4 s = {0.f, 0.f, 0.f, 0.f};
    const float4* z4 = (const float4*)z;
    ushort4* h4 = (ushort4*)hbf;
    for (int r = lo + rg; r < hi; r += 8) {
        float4 v = z4[r * 64 + q];
        v.x = v.x * sc.x + sh.x;
        v.y = v.y * sc.y + sh.y;
        v.z = v.z * sc.z + sh.z;
        v.w = v.w * sc.w + sh.w;
        s.x += v.x; s.y += v.y; s.z += v.z; s.w += v.w;
        ushort4 o;
        o.x = f2bf(v.x); o.y = f2bf(v.y); o.z = f2bf(v.z); o.w = f2bf(v.w);
        h4[r * 64 + q] = o;
    }
    red[rg][q] = s;
    __syncthreads();
    if (rg < 4) {
        float4 a = red[rg][q], b = red[rg + 4][q];
        a.x += b.x; a.y += b.y; a.z += b.z; a.w += b.w;
        red[rg][q] = a;
    }
    __syncthreads();
    if (rg < 2) {
        float4 a = red[rg][q], b = red[rg + 2][q];
        a.x += b.x; a.y += b.y; a.z += b.z; a.w += b.w;
        red[rg][q] = a;
    }
    __syncthreads();
    if (rg == 0) {
        float4 a = red[0][q], b = red[1][q];
        a.x += b.x; a.y += b.y; a.z += b.z; a.w += b.w;
        ((float4*)(out + (size_t)g * (NL * DD) + layer * DD))[q] = a;
    }
}

extern "C" void kernel_launch(void* const* d_in, const int* in_sizes, int n_in,
                              void* d_out, int out_size, void* d_ws, size_t ws_size,
                              hipStream_t stream) {
    const float* x     = (const float*)d_in[0];
    const int*   ei    = (const int*)d_in[1];
    const int*   batch = (const int*)d_in[2];
    const float* w1    = (const float*)d_in[3];
    const float* b1    = (const float*)d_in[4];
    const float* w2    = (const float*)d_in[5];
    const float* b2    = (const float*)d_in[6];
    const float* gamma = (const float*)d_in[7];
    const float* beta  = (const float*)d_in[8];
    float* out = (float*)d_out;

    char* ws = (char*)d_ws;
    size_t off = 0;
    auto alloc = [&](size_t bytes) -> void* {
        void* p = ws + off;
        off += (bytes + 255) & ~size_t(255);
        return p;
    };
    float*          buf0 = (float*)alloc((size_t)MPAD * DD * 4);          // fp32 GEMM2 out
    unsigned short* zbf  = (unsigned short*)alloc((size_t)MPAD * DD * 2); // agg out (GEMM1 A)
    unsigned short* h1bf = (unsigned short*)alloc((size_t)MPAD * DD * 2); // GEMM1 out (GEMM2 A)
    unsigned short* hbf  = (unsigned short*)alloc((size_t)NN * DD * 2);   // h as bf16
    unsigned short* wt   = (unsigned short*)alloc((size_t)6 * DD * DD * 2);
    int* deg    = (int*)alloc((size_t)NN * 4);
    unsigned short* elist = (unsigned short*)alloc((size_t)NN * CAP * 2);
    int* gstart = (int*)alloc((size_t)(NG + 1) * 4);
    float* pstat = (float*)alloc((size_t)NMB * 512 * 4);
    float* ss   = (float*)alloc(2 * DD * 4);

    // CSR (one atomic pass) + graph boundaries (binary search)
    k_init<<<(NN + 255) / 256, 256, 0, stream>>>(deg);
    k_scatter<<<(NE + 255) / 256, 256, 0, stream>>>(ei, deg, elist);
    k_gbounds<<<1, 256, 0, stream>>>(batch, gstart);

    // weight transpose+convert, x -> bf16, zero pad rows of zbf
    k_wconv<<<(6 * 65536 + 255) / 256, 256, 0, stream>>>(w1, w2, wt);
    k_f2bf<<<(NN * DD / 4 + 255) / 256, 256, 0, stream>>>(x, hbf, NN * DD / 4);
    k_zpad<<<((MPAD - NN) * DD + 255) / 256, 256, 0, stream>>>(zbf);

    dim3 ggrid(MPAD / GBM, DD / GBM);
    for (int l = 0; l < NL; ++l) {
        k_agg_bf<<<NN, 64, 0, stream>>>(hbf, deg, elist, zbf);
        k_mfma_gemm<1, 0><<<ggrid, 256, 0, stream>>>(zbf, wt + (size_t)l * DD * DD, b1 + l * DD, h1bf, nullptr);
        k_mfma_gemm<0, 1><<<ggrid, 256, 0, stream>>>(h1bf, wt + (size_t)(3 + l) * DD * DD, b2 + l * DD, buf0, pstat);
        k_bnscale2<<<DD, 256, 0, stream>>>(pstat, gamma + l * DD, beta + l * DD, ss);
        k_bnpool<<<NG, 512, 0, stream>>>(buf0, ss, gstart, hbf, out, l);
    }
}